// Round 1
// baseline (358.739 us; speedup 1.0000x reference)
//
#include <hip/hip_runtime.h>

// ZeroWeave: x[B,C,64,64] -> out[B,C,190,190], out[:,:,::3,::3]=x, rest 0.
// B=32, C=64, s=3. out = 295.7 MB, x = 33.5 MB -> memory floor ~52 us @6.3 TB/s.
//
// R5 analysis: dur_us(328) = harness poison fill (~193 us, 1.18 GB @6.2 TB/s,
// top-5 dispatches) + kernel (~135 us, ~2.4 TB/s). R3 (branchy) == R4
// (branchless table) in time -> not VALU-bound; common cost is the per-slot
// serial LDS chain (tab ds_read -> data ds_reads -> cndmask) + launch_bounds
// (256,8) VGPR squeeze, paid even though 66% of slots are statically zero.
//
// R5: run-structure decomposition, no LDS, no table, no inner-loop divides.
// Pattern group (6 out rows = 285 float4): [0..47 data][48..141 zero]
// [142..189 data][190..284 zero]. Plane = 31 full groups + partial group
// (rows 186..189 = pattern slots 0..189).
// 12-float periodicity (LCM(3,4)) => each data slot is one of 3 classes:
//   cls0: {fa,0,0,fb}   cls1: {0,0,fa,0}   cls2: {0,fb,0,0}
// fed by one aligned float2 load from x. Per-thread class/offsets are
// loop-invariant: data inner loop = 1 load + 4 cndmask + 1 store.
// Zero phase: thread t owns one fixed zero slot of the pattern; loop over
// groups = 1 store + 1 add per slot.
//
// Verified mapping (half = pattern row 0 vs row 3, x row = 2g+half):
//   half=0: m=0 -> cls0 reads x[4c,4c+1]; m=1 -> cls1 reads x[4c+2];
//           m=2 -> cls2 reads x[4c+3]        (load offset 4c + 2*(m!=0))
//   half=1: m=0 -> cls1 reads x[4c]; m=1 -> cls2 reads x[4c+1];
//           m=2 -> cls0 reads x[4c+2,4c+3]   (load offset 4c + 2*(m==2))
// Slot within group: q = r (r<48) or 142+(r-48) = 94+r.

constexpr int NPLANES    = 32 * 64;   // 2048
constexpr int BLOCK      = 192;       // 3 waves: 2x96 data slots, 189 zero slots
constexpr int PLANE_IN_F = 64 * 64;   // 4096 floats
constexpr int PLANE_OUT4 = 9025;      // 190*190/4 float4
constexpr int GROUPS     = 31;        // full 6-row groups (rows 0..185)

__global__ __launch_bounds__(BLOCK) void ZeroWeave_89601607729830_kernel(
    const float* __restrict__ x, float* __restrict__ out) {
    const int bc = blockIdx.x;
    const int t  = threadIdx.x;

    const float* xp = x + (size_t)bc * PLANE_IN_F;
    float4* op = reinterpret_cast<float4*>(out) + (size_t)bc * PLANE_OUT4;

    // ---- data phase: 192 threads cover 2 groups/iter, 16 iters (g = 2k+hi).
    // All per-thread pattern math is loop-invariant.
    {
        const int hi   = (t >= 96) ? 1 : 0;   // which of the 2 groups
        const int r    = t - 96 * hi;         // data slot in pattern, 0..95
        const int half = (r >= 48) ? 1 : 0;   // 0: pattern row 0, 1: pattern row 3
        const int rr   = r - 48 * half;       // 0..47
        const unsigned c = (unsigned)rr / 3u;         // x float4-chunk, 0..15
        const unsigned m = (unsigned)rr - 3u * c;
        unsigned cls = m + (unsigned)half;
        if (cls >= 3u) cls -= 3u;
        const int sel2 = half ? (m == 2u) : (m != 0u);
        const int xoff = half * 64 + 4 * (int)c + 2 * sel2; // float offset in x row-pair
        const int qofs = r + (half ? 94 : 0);               // slot within group
        const bool p0 = (cls == 0u), p1 = (cls == 1u), p2 = (cls == 2u);

        const float* xa = xp + xoff;   // + g*128 per group
        float4* oa = op + qofs;        // + g*285 per group
#pragma unroll 4
        for (int k = 0; k < 16; ++k) {
            const int g = 2 * k + hi;
            const float2 v = *reinterpret_cast<const float2*>(xa + g * 128);
            float4 o;
            o.x = p0 ? v.x : 0.0f;
            o.y = p2 ? v.y : 0.0f;
            o.z = p1 ? v.x : 0.0f;
            o.w = p0 ? v.y : 0.0f;
            oa[g * 285] = o;
        }
    }

    // ---- zero phase: thread t owns one fixed zero-slot position.
    // Full groups: slots 48..141 and 190..284 (189). Partial group: 48..141.
    {
        const float4 z = make_float4(0.0f, 0.0f, 0.0f, 0.0f);
        if (t < 189) {
            const int myq = 48 + t + ((t >= 94) ? 48 : 0); // 48..141, 190..284
            float4* o = op + myq;
#pragma unroll
            for (int g = 0; g < GROUPS; ++g)
                o[g * 285] = z;
            if (t < 94)                 // partial group (g=31): only 48..141
                o[GROUPS * 285] = z;
        }
    }
}

extern "C" void kernel_launch(void* const* d_in, const int* in_sizes, int n_in,
                              void* d_out, int out_size, void* d_ws, size_t ws_size,
                              hipStream_t stream) {
    const float* x = (const float*)d_in[0];
    // d_in[1] is num_zeros (==2), baked into constants.
    float* out = (float*)d_out;

    ZeroWeave_89601607729830_kernel<<<NPLANES, BLOCK, 0, stream>>>(x, out);
}

// Round 3
// 342.174 us; speedup vs baseline: 1.0484x; 1.0484x over previous
//
#include <hip/hip_runtime.h>

// ZeroWeave: x[B,C,64,64] -> out[B,C,190,190], out[:,:,::3,::3]=x, rest 0.
// B=32, C=64, s=3. out = 295.7 MB, x = 33.5 MB -> memory floor ~52 us @6.3 TB/s.
//
// R6 theory: R3 (branchy) ~= R4 (LDS table, linear writes) ~= R5 (register
// compose, strided writes) at ~2.2-2.6 TB/s despite >2x differences in
// per-slot instruction count and completely different store orders. Not
// VALU-, issue-, or occupancy-bound; CUs sit at <10% of their store-port
// capability -> memory-system backpressure. The one thing all three share
// and the 6.2 TB/s rocclr fill (same width, same chip, same graph) doesn't:
// plain stores write-ALLOCATE in L2 + 256 MB L3. out (295.7 MB ~ L3 size)
// is never re-read, so the whole stream is L3 dirty-line churn
// (allocate->evict->writeback ~doubles internal write traffic). R6 = R5
// structure, stores/loads marked nontemporal (global_store_* nt) to stream
// past the caches like the fill does.
//
// R7 fix: __builtin_nontemporal_* requires clang ext_vector types, not
// HIP_vector_type (float4/float2 are classes) -> use f32x4/f32x2 typedefs.
//
// Pattern group (6 out rows = 285 float4): [0..47 data][48..141 zero]
// [142..189 data][190..284 zero]. Plane = 31 full groups + partial group
// (rows 186..189 = pattern slots 0..189).
// 12-float periodicity (LCM(3,4)) => each data slot is one of 3 classes:
//   cls0: {fa,0,0,fb}   cls1: {0,0,fa,0}   cls2: {0,fb,0,0}
// fed by one aligned float2 load from x. Per-thread class/offsets are
// loop-invariant: data inner loop = 1 load + 4 cndmask + 1 store.
// Zero phase: thread t owns one fixed zero slot of the pattern; loop over
// groups = 1 store + 1 add per slot.
//
// Verified mapping (half = pattern row 0 vs row 3, x row = 2g+half):
//   half=0: m=0 -> cls0 reads x[4c,4c+1]; m=1 -> cls1 reads x[4c+2];
//           m=2 -> cls2 reads x[4c+3]        (load offset 4c + 2*(m!=0))
//   half=1: m=0 -> cls1 reads x[4c]; m=1 -> cls2 reads x[4c+1];
//           m=2 -> cls0 reads x[4c+2,4c+3]   (load offset 4c + 2*(m==2))
// Slot within group: q = r (r<48) or 142+(r-48) = 94+r.

typedef float f32x4 __attribute__((ext_vector_type(4)));
typedef float f32x2 __attribute__((ext_vector_type(2)));

constexpr int NPLANES    = 32 * 64;   // 2048
constexpr int BLOCK      = 192;       // 3 waves: 2x96 data slots, 189 zero slots
constexpr int PLANE_IN_F = 64 * 64;   // 4096 floats
constexpr int PLANE_OUT4 = 9025;      // 190*190/4 float4
constexpr int GROUPS     = 31;        // full 6-row groups (rows 0..185)

__global__ __launch_bounds__(BLOCK) void ZeroWeave_89601607729830_kernel(
    const float* __restrict__ x, float* __restrict__ out) {
    const int bc = blockIdx.x;
    const int t  = threadIdx.x;

    const float* xp = x + (size_t)bc * PLANE_IN_F;
    f32x4* op = reinterpret_cast<f32x4*>(out) + (size_t)bc * PLANE_OUT4;

    // ---- data phase: 192 threads cover 2 groups/iter, 16 iters (g = 2k+hi).
    // All per-thread pattern math is loop-invariant.
    {
        const int hi   = (t >= 96) ? 1 : 0;   // which of the 2 groups
        const int r    = t - 96 * hi;         // data slot in pattern, 0..95
        const int half = (r >= 48) ? 1 : 0;   // 0: pattern row 0, 1: pattern row 3
        const int rr   = r - 48 * half;       // 0..47
        const unsigned c = (unsigned)rr / 3u;         // x float4-chunk, 0..15
        const unsigned m = (unsigned)rr - 3u * c;
        unsigned cls = m + (unsigned)half;
        if (cls >= 3u) cls -= 3u;
        const int sel2 = half ? (m == 2u) : (m != 0u);
        const int xoff = half * 64 + 4 * (int)c + 2 * sel2; // float offset in x row-pair
        const int qofs = r + (half ? 94 : 0);               // slot within group
        const bool p0 = (cls == 0u), p1 = (cls == 1u), p2 = (cls == 2u);

        const float* xa = xp + xoff;   // + g*128 per group
        f32x4* oa = op + qofs;         // + g*285 per group
#pragma unroll 4
        for (int k = 0; k < 16; ++k) {
            const int g = 2 * k + hi;
            const f32x2 v = __builtin_nontemporal_load(
                reinterpret_cast<const f32x2*>(xa + g * 128));
            f32x4 o;
            o.x = p0 ? v.x : 0.0f;
            o.y = p2 ? v.y : 0.0f;
            o.z = p1 ? v.x : 0.0f;
            o.w = p0 ? v.y : 0.0f;
            __builtin_nontemporal_store(o, &oa[g * 285]);
        }
    }

    // ---- zero phase: thread t owns one fixed zero-slot position.
    // Full groups: slots 48..141 and 190..284 (189). Partial group: 48..141.
    {
        const f32x4 z = {0.0f, 0.0f, 0.0f, 0.0f};
        if (t < 189) {
            const int myq = 48 + t + ((t >= 94) ? 48 : 0); // 48..141, 190..284
            f32x4* o = op + myq;
#pragma unroll
            for (int g = 0; g < GROUPS; ++g)
                __builtin_nontemporal_store(z, &o[g * 285]);
            if (t < 94)                 // partial group (g=31): only 48..141
                __builtin_nontemporal_store(z, &o[GROUPS * 285]);
        }
    }
}

extern "C" void kernel_launch(void* const* d_in, const int* in_sizes, int n_in,
                              void* d_out, int out_size, void* d_ws, size_t ws_size,
                              hipStream_t stream) {
    const float* x = (const float*)d_in[0];
    // d_in[1] is num_zeros (==2), baked into constants.
    float* out = (float*)d_out;

    ZeroWeave_89601607729830_kernel<<<NPLANES, BLOCK, 0, stream>>>(x, out);
}